// Round 21
// baseline (140.414 us; speedup 1.0000x reference)
//
#include <hip/hip_runtime.h>
#include <math.h>
#include <string.h>

// piSGC R21: R20 + y-table eliminated (final reconstructs y = z1*rdis) +
// part_scatter CHUNK 4096 (391 blocks x 1024t; R13 showed parallelism-starved).
// Lineage: CSR-gather, scan-free reservation build, packed 4B csr, bf16 z
// tables with diagonal push-through, 10-lane/node spmv, NT output stores.

#define ALPHA  0.05f
#define SCALE  0.475f   // (1 - ALPHA) / NUM_LAYERS
#define FDIM   64
#define CDIM   40
#define NPAD   131072
#define CHUNK  4096
#define BCAP   10240
#define SRCMASK 0x1FFFFu

__device__ __forceinline__ unsigned short f2bf(float f) {
    unsigned u = __float_as_uint(f);
    unsigned r = (u + 0x7FFFu + ((u >> 16) & 1u)) >> 16;   // round-nearest-even
    return (unsigned short)r;
}
__device__ __forceinline__ float bfLo(unsigned u) { return __uint_as_float(u << 16); }
__device__ __forceinline__ float bfHi(unsigned u) { return __uint_as_float(u & 0xffff0000u); }
__device__ __forceinline__ float wUnpack(unsigned v) {
    return __uint_as_float((v >> 17) << 16);
}

// ---- zero the 256-entry alloc array ----
__global__ __launch_bounds__(256) void zero_alloc(int* __restrict__ alloc) {
    alloc[threadIdx.x] = 0;
}

// ---- part_scatter: hist chunk -> reserve ranges -> scatter packed payload ----
__global__ __launch_bounds__(1024) void part_scatter(
        const int* __restrict__ row, const int* __restrict__ col,
        const float* __restrict__ ea, int* __restrict__ alloc,
        int2* __restrict__ ppay, int E) {
    __shared__ unsigned h[256];
    __shared__ unsigned offs[256];
    int tid = threadIdx.x, blk = blockIdx.x;
    if (tid < 256) h[tid] = 0;
    __syncthreads();
    int base = blk * CHUNK;
    int end  = min(base + CHUNK, E);
    for (int e = base + tid; e < end; e += 1024)
        atomicAdd(&h[col[e] >> 9], 1u);
    __syncthreads();
    if (tid < 256) {
        unsigned hc = h[tid];
        unsigned r = hc ? (unsigned)atomicAdd(&alloc[tid], (int)hc) : 0u;
        offs[tid] = (unsigned)(tid * BCAP) + r;
    }
    __syncthreads();
    for (int e = base + tid; e < end; e += 1024) {
        int c = col[e];
        int bin = c >> 9;
        unsigned p = atomicAdd(&offs[bin], 1u);
        if (p < (unsigned)((bin + 1) * BCAP))
            ppay[p] = make_int2(row[e] | ((c & 511) << 20), __float_as_int(ea[e]));
    }
}

// ---- bucket_csr: per-bucket finalize; writes start, csr, dis AND rdis ----
__global__ __launch_bounds__(256) void bucket_csr(
        const int2* __restrict__ ppay, const int* __restrict__ alloc,
        int* __restrict__ start, unsigned* __restrict__ csr,
        float* __restrict__ dis, float* __restrict__ rdis, int N) {
    __shared__ unsigned cnt8[512][8];
    __shared__ unsigned ps[256], exc[512];
    __shared__ float sdeg[512];
    __shared__ int sAll[256];
    int tid = threadIdx.x, k = blockIdx.x;

    int myCnt = min(alloc[tid], BCAP);
    sAll[tid] = myCnt;
    __syncthreads();
    for (int off = 1; off < 256; off <<= 1) {
        int t = (tid >= off) ? sAll[tid - off] : 0;
        __syncthreads();
        sAll[tid] += t;
        __syncthreads();
    }
    int cnt = min(alloc[k], BCAP);
    int e0  = sAll[k] - cnt;
    const int2* src = ppay + (size_t)k * BCAP;

    for (int i = tid; i < 4096; i += 256) ((unsigned*)cnt8)[i] = 0;
    sdeg[tid] = 0.0f; sdeg[tid + 256] = 0.0f;
    __syncthreads();

    for (int j = tid; j < cnt; j += 256) {
        int2 pay = src[j];
        int c = (pay.x >> 20) & 511;
        atomicAdd(&cnt8[c][(pay.x & 0xFFFFF) >> 14], 1u);
        atomicAdd(&sdeg[c], __int_as_float(pay.y));
    }
    __syncthreads();

    int c0 = 2 * tid, c1 = 2 * tid + 1;
    unsigned t0 = 0, t1 = 0;
    #pragma unroll
    for (int o = 0; o < 8; ++o) { t0 += cnt8[c0][o]; t1 += cnt8[c1][o]; }
    unsigned pair = t0 + t1;
    ps[tid] = pair;
    __syncthreads();
    for (int off = 1; off < 256; off <<= 1) {
        unsigned t = (tid >= off) ? ps[tid - off] : 0;
        __syncthreads();
        ps[tid] += t;
        __syncthreads();
    }
    unsigned pexc = ps[tid] - pair;
    exc[c0] = pexc;
    exc[c1] = pexc + t0;
    unsigned b = pexc;
    #pragma unroll
    for (int o = 0; o < 8; ++o) { unsigned t = cnt8[c0][o]; cnt8[c0][o] = b; b += t; }
    b = pexc + t0;
    #pragma unroll
    for (int o = 0; o < 8; ++o) { unsigned t = cnt8[c1][o]; cnt8[c1][o] = b; b += t; }
    __syncthreads();

    #pragma unroll
    for (int i = tid; i < 512; i += 256) {
        int g = k * 512 + i;
        if (g <= N) start[g] = e0 + (int)exc[i];
        if (g < N) {
            float d = sdeg[i];
            bool pos = (d > 0.0f);
            float dc = fmaxf(d, 1e-12f);
            dis[g]  = pos ? rsqrtf(dc) : 0.0f;
            rdis[g] = pos ? sqrtf(dc)  : 0.0f;    // 1/dis
        }
    }

    for (int j = tid; j < cnt; j += 256) {
        int2 pay = src[j];
        int c    = (pay.x >> 20) & 511;
        int srcn = pay.x & 0xFFFFF;
        unsigned p = atomicAdd(&cnt8[c][srcn >> 14], 1u);
        unsigned wbf = (unsigned)f2bf(__int_as_float(pay.y));   // raw ea >= 0
        csr[e0 + p] = (unsigned)srcn | (wbf << 17);
    }
}

// ---- lin: writes ONLY z1 = dis * (x @ W). 4 threads/node x 10 outputs ----
__global__ __launch_bounds__(256) void lin_kernel(
        const float* __restrict__ x, const float* __restrict__ W,
        const float* __restrict__ dis,
        unsigned* __restrict__ z1, int N) {
    __shared__ float sWt[CDIM][FDIM + 4];
    for (int i = threadIdx.x; i < FDIM * CDIM; i += 256) {
        int k = i / CDIM, c = i - k * CDIM;
        sWt[c][k] = W[i];
    }
    __syncthreads();

    int t = threadIdx.x;
    int node = blockIdx.x * 64 + (t >> 2);
    if (node >= N) return;
    int cs = (t & 3) * 10;

    float acc[10];
    #pragma unroll
    for (int i = 0; i < 10; ++i) acc[i] = 0.0f;

    const float4* xr = (const float4*)(x + (size_t)node * FDIM);
    #pragma unroll
    for (int k4 = 0; k4 < FDIM / 4; ++k4) {
        float4 v = xr[k4];
        #pragma unroll
        for (int i = 0; i < 10; ++i) {
            const float4 w = *(const float4*)&sWt[cs + i][k4 * 4];
            acc[i] = fmaf(v.x, w.x, fmaf(v.y, w.y, fmaf(v.z, w.z, fmaf(v.w, w.w, acc[i]))));
        }
    }

    float dn = dis[node];
    unsigned* zr = z1 + (size_t)node * 20 + (t & 3) * 5;
    #pragma unroll
    for (int k = 0; k < 5; ++k)
        zr[k] = (unsigned)f2bf(dn * acc[2 * k]) | ((unsigned)f2bf(dn * acc[2 * k + 1]) << 16);
}

// ---- spmv1: t = A_ea^T z1; store ONLY z2 = dis^2 * t ----
__global__ __launch_bounds__(256) void spmv_kernel(
        const unsigned* __restrict__ z1, const int* __restrict__ start,
        const unsigned* __restrict__ csr, const float* __restrict__ dis,
        unsigned* __restrict__ z2, int N) {
    int lane = threadIdx.x & 63;
    int wid  = threadIdx.x >> 6;
    int grp  = lane / 10;            // 0..5 active; lanes 60-63 idle
    int grel = lane - grp * 10;
    int node = blockIdx.x * 24 + wid * 6 + grp;
    bool act = (grp < 6) && (node < N);

    int e0 = 0, e1 = 0;
    if (act) { e0 = start[node]; e1 = start[node + 1]; }
    const uint2* gin2 = (const uint2*)z1;

    float a0 = 0, a1 = 0, a2 = 0, a3 = 0;
    float b0 = 0, b1 = 0, b2 = 0, b3 = 0;
    int j = e0;
    for (; j + 7 < e1; j += 8) {
        unsigned v0 = csr[j],     v1 = csr[j + 1], v2 = csr[j + 2], v3 = csr[j + 3];
        unsigned v4 = csr[j + 4], v5 = csr[j + 5], v6 = csr[j + 6], v7 = csr[j + 7];
        uint2 u0 = gin2[(size_t)(v0 & SRCMASK) * 10 + grel];
        uint2 u1 = gin2[(size_t)(v1 & SRCMASK) * 10 + grel];
        uint2 u2 = gin2[(size_t)(v2 & SRCMASK) * 10 + grel];
        uint2 u3 = gin2[(size_t)(v3 & SRCMASK) * 10 + grel];
        uint2 u4 = gin2[(size_t)(v4 & SRCMASK) * 10 + grel];
        uint2 u5 = gin2[(size_t)(v5 & SRCMASK) * 10 + grel];
        uint2 u6 = gin2[(size_t)(v6 & SRCMASK) * 10 + grel];
        uint2 u7 = gin2[(size_t)(v7 & SRCMASK) * 10 + grel];
        float w0 = wUnpack(v0), w1 = wUnpack(v1), w2 = wUnpack(v2), w3 = wUnpack(v3);
        float w4 = wUnpack(v4), w5 = wUnpack(v5), w6 = wUnpack(v6), w7 = wUnpack(v7);
        a0 = fmaf(w0, bfLo(u0.x), a0); a1 = fmaf(w0, bfHi(u0.x), a1);
        a2 = fmaf(w0, bfLo(u0.y), a2); a3 = fmaf(w0, bfHi(u0.y), a3);
        b0 = fmaf(w1, bfLo(u1.x), b0); b1 = fmaf(w1, bfHi(u1.x), b1);
        b2 = fmaf(w1, bfLo(u1.y), b2); b3 = fmaf(w1, bfHi(u1.y), b3);
        a0 = fmaf(w2, bfLo(u2.x), a0); a1 = fmaf(w2, bfHi(u2.x), a1);
        a2 = fmaf(w2, bfLo(u2.y), a2); a3 = fmaf(w2, bfHi(u2.y), a3);
        b0 = fmaf(w3, bfLo(u3.x), b0); b1 = fmaf(w3, bfHi(u3.x), b1);
        b2 = fmaf(w3, bfLo(u3.y), b2); b3 = fmaf(w3, bfHi(u3.y), b3);
        a0 = fmaf(w4, bfLo(u4.x), a0); a1 = fmaf(w4, bfHi(u4.x), a1);
        a2 = fmaf(w4, bfLo(u4.y), a2); a3 = fmaf(w4, bfHi(u4.y), a3);
        b0 = fmaf(w5, bfLo(u5.x), b0); b1 = fmaf(w5, bfHi(u5.x), b1);
        b2 = fmaf(w5, bfLo(u5.y), b2); b3 = fmaf(w5, bfHi(u5.y), b3);
        a0 = fmaf(w6, bfLo(u6.x), a0); a1 = fmaf(w6, bfHi(u6.x), a1);
        a2 = fmaf(w6, bfLo(u6.y), a2); a3 = fmaf(w6, bfHi(u6.y), a3);
        b0 = fmaf(w7, bfLo(u7.x), b0); b1 = fmaf(w7, bfHi(u7.x), b1);
        b2 = fmaf(w7, bfLo(u7.y), b2); b3 = fmaf(w7, bfHi(u7.y), b3);
    }
    for (; j < e1; ++j) {
        unsigned v = csr[j];
        uint2 u = gin2[(size_t)(v & SRCMASK) * 10 + grel];
        float w = wUnpack(v);
        a0 = fmaf(w, bfLo(u.x), a0); a1 = fmaf(w, bfHi(u.x), a1);
        a2 = fmaf(w, bfLo(u.y), a2); a3 = fmaf(w, bfHi(u.y), a3);
    }
    if (act) {
        float dn = dis[node];
        float d2 = dn * dn;
        float z0 = d2 * (a0 + b0), zz1 = d2 * (a1 + b1);
        float z2v = d2 * (a2 + b2), z3 = d2 * (a3 + b3);
        uint2 oz;
        oz.x = (unsigned)f2bf(z0)  | ((unsigned)f2bf(zz1) << 16);
        oz.y = (unsigned)f2bf(z2v) | ((unsigned)f2bf(z3) << 16);
        ((uint2*)z2)[(size_t)node * 10 + grel] = oz;
    }
}

// ---- conv2 + log_softmax; y and g1 reconstructed via rdis ----
__global__ __launch_bounds__(256) void spmv_final_kernel(
        const unsigned* __restrict__ z2, const unsigned* __restrict__ z1,
        const float* __restrict__ bias, const int* __restrict__ start,
        const unsigned* __restrict__ csr, const float* __restrict__ dis,
        const float* __restrict__ rdis, float* __restrict__ out, int N) {
    int lane = threadIdx.x & 63;
    int wid  = threadIdx.x >> 6;
    int grp  = lane / 10;
    int grel = lane - grp * 10;
    int node = blockIdx.x * 24 + wid * 6 + grp;
    bool act = (grp < 6) && (node < N);

    int e0 = 0, e1 = 0;
    if (act) { e0 = start[node]; e1 = start[node + 1]; }
    const uint2* g22 = (const uint2*)z2;

    float a0 = 0, a1 = 0, a2 = 0, a3 = 0;
    float b0 = 0, b1 = 0, b2 = 0, b3 = 0;
    int j = e0;
    for (; j + 7 < e1; j += 8) {
        unsigned v0 = csr[j],     v1 = csr[j + 1], v2 = csr[j + 2], v3 = csr[j + 3];
        unsigned v4 = csr[j + 4], v5 = csr[j + 5], v6 = csr[j + 6], v7 = csr[j + 7];
        uint2 u0 = g22[(size_t)(v0 & SRCMASK) * 10 + grel];
        uint2 u1 = g22[(size_t)(v1 & SRCMASK) * 10 + grel];
        uint2 u2 = g22[(size_t)(v2 & SRCMASK) * 10 + grel];
        uint2 u3 = g22[(size_t)(v3 & SRCMASK) * 10 + grel];
        uint2 u4 = g22[(size_t)(v4 & SRCMASK) * 10 + grel];
        uint2 u5 = g22[(size_t)(v5 & SRCMASK) * 10 + grel];
        uint2 u6 = g22[(size_t)(v6 & SRCMASK) * 10 + grel];
        uint2 u7 = g22[(size_t)(v7 & SRCMASK) * 10 + grel];
        float w0 = wUnpack(v0), w1 = wUnpack(v1), w2 = wUnpack(v2), w3 = wUnpack(v3);
        float w4 = wUnpack(v4), w5 = wUnpack(v5), w6 = wUnpack(v6), w7 = wUnpack(v7);
        a0 = fmaf(w0, bfLo(u0.x), a0); a1 = fmaf(w0, bfHi(u0.x), a1);
        a2 = fmaf(w0, bfLo(u0.y), a2); a3 = fmaf(w0, bfHi(u0.y), a3);
        b0 = fmaf(w1, bfLo(u1.x), b0); b1 = fmaf(w1, bfHi(u1.x), b1);
        b2 = fmaf(w1, bfLo(u1.y), b2); b3 = fmaf(w1, bfHi(u1.y), b3);
        a0 = fmaf(w2, bfLo(u2.x), a0); a1 = fmaf(w2, bfHi(u2.x), a1);
        a2 = fmaf(w2, bfLo(u2.y), a2); a3 = fmaf(w2, bfHi(u2.y), a3);
        b0 = fmaf(w3, bfLo(u3.x), b0); b1 = fmaf(w3, bfHi(u3.x), b1);
        b2 = fmaf(w3, bfLo(u3.y), b2); b3 = fmaf(w3, bfHi(u3.y), b3);
        a0 = fmaf(w4, bfLo(u4.x), a0); a1 = fmaf(w4, bfHi(u4.x), a1);
        a2 = fmaf(w4, bfLo(u4.y), a2); a3 = fmaf(w4, bfHi(u4.y), a3);
        b0 = fmaf(w5, bfLo(u5.x), b0); b1 = fmaf(w5, bfHi(u5.x), b1);
        b2 = fmaf(w5, bfLo(u5.y), b2); b3 = fmaf(w5, bfHi(u5.y), b3);
        a0 = fmaf(w6, bfLo(u6.x), a0); a1 = fmaf(w6, bfHi(u6.x), a1);
        a2 = fmaf(w6, bfLo(u6.y), a2); a3 = fmaf(w6, bfHi(u6.y), a3);
        b0 = fmaf(w7, bfLo(u7.x), b0); b1 = fmaf(w7, bfHi(u7.x), b1);
        b2 = fmaf(w7, bfLo(u7.y), b2); b3 = fmaf(w7, bfHi(u7.y), b3);
    }
    for (; j < e1; ++j) {
        unsigned v = csr[j];
        uint2 u = g22[(size_t)(v & SRCMASK) * 10 + grel];
        float w = wUnpack(v);
        a0 = fmaf(w, bfLo(u.x), a0); a1 = fmaf(w, bfHi(u.x), a1);
        a2 = fmaf(w, bfLo(u.y), a2); a3 = fmaf(w, bfHi(u.y), a3);
    }

    float l0 = 0, l1 = 0, l2 = 0, l3 = 0;
    if (act) {
        float dn = dis[node];
        float rd = rdis[node];
        float g20 = dn * (a0 + b0), g21 = dn * (a1 + b1);
        float g22v = dn * (a2 + b2), g23 = dn * (a3 + b3);
        uint2 z1u = ((const uint2*)z1)[(size_t)node * 10 + grel];
        uint2 zu  = g22[(size_t)node * 10 + grel];
        // y = z1*rdis ; g1 = z2*rdis
        float y0 = bfLo(z1u.x) * rd, y1 = bfHi(z1u.x) * rd;
        float y2 = bfLo(z1u.y) * rd, y3 = bfHi(z1u.y) * rd;
        float g10 = bfLo(zu.x) * rd, g11 = bfHi(zu.x) * rd;
        float g12 = bfLo(zu.y) * rd, g13 = bfHi(zu.y) * rd;
        float4 bv = *(const float4*)&bias[4 * grel];
        l0 = fmaf(ALPHA, y0, fmaf(SCALE, g10 + g20, bv.x));
        l1 = fmaf(ALPHA, y1, fmaf(SCALE, g11 + g21, bv.y));
        l2 = fmaf(ALPHA, y2, fmaf(SCALE, g12 + g22v, bv.z));
        l3 = fmaf(ALPHA, y3, fmaf(SCALE, g13 + g23, bv.w));
    }

    float m = act ? fmaxf(fmaxf(l0, l1), fmaxf(l2, l3)) : -INFINITY;
    #pragma unroll
    for (int off = 8; off; off >>= 1) {
        float o = __shfl(m, lane + off);
        if (grel + off < 10) m = fmaxf(m, o);
    }
    m = __shfl(m, grp * 10);

    float ex = act ? (expf(l0 - m) + expf(l1 - m) + expf(l2 - m) + expf(l3 - m)) : 0.0f;
    #pragma unroll
    for (int off = 8; off; off >>= 1) {
        float o = __shfl(ex, lane + off);
        if (grel + off < 10) ex += o;
    }
    ex = __shfl(ex, grp * 10);

    if (act) {
        float lse = m + logf(ex);
        float2 oA, oB;
        oA.x = l0 - lse; oA.y = l1 - lse;
        oB.x = l2 - lse; oB.y = l3 - lse;
        double dA, dB;
        memcpy(&dA, &oA, 8);
        memcpy(&dB, &oB, 8);
        double* p = (double*)&out[(size_t)node * CDIM + 4 * grel];
        __builtin_nontemporal_store(dA, p);
        __builtin_nontemporal_store(dB, p + 1);
    }
}

extern "C" void kernel_launch(void* const* d_in, const int* in_sizes, int n_in,
                              void* d_out, int out_size, void* d_ws, size_t ws_size,
                              hipStream_t stream) {
    const float* x  = (const float*)d_in[0];   // [N,64]
    const float* ea = (const float*)d_in[1];   // [E]
    const float* W  = (const float*)d_in[2];   // [64,40]
    const float* b  = (const float*)d_in[3];   // [40]
    const int*   ei = (const int*)d_in[4];     // [2,E]: row then col

    const int N = in_sizes[0] / FDIM;
    const int E = in_sizes[1];
    const int* row = ei;
    const int* col = ei + E;

    const int NBLK = (E + CHUNK - 1) / CHUNK;

    // workspace layout (4-byte words; every used region fully written each call)
    int*   startp = (int*)d_ws;                    // NPAD
    float* dis    = (float*)(startp + NPAD);       // NPAD
    float* rdis   = dis + NPAD;                    // NPAD
    int*   alloc  = (int*)(rdis + NPAD);           // 1024 (256 used)
    int2*  ppay   = (int2*)(alloc + 1024);         // 256*BCAP int2 (~21 MB)
    unsigned* csr = (unsigned*)(ppay + 256 * BCAP); // E packed dwords
    unsigned* z2bf = csr + E;                      // N*20 dwords
    unsigned* z1bf = (unsigned*)ppay;              // aliases ppay (dead after bucket_csr)

    zero_alloc  <<<1, 256, 0, stream>>>(alloc);
    part_scatter<<<NBLK, 1024, 0, stream>>>(row, col, ea, alloc, ppay, E);
    bucket_csr  <<<256, 256, 0, stream>>>(ppay, alloc, startp, csr, dis, rdis, N);
    lin_kernel  <<<(N + 63) / 64, 256, 0, stream>>>(x, W, dis, z1bf, N);

    int spmv_blocks = (N + 23) / 24;
    spmv_kernel      <<<spmv_blocks, 256, 0, stream>>>(z1bf, startp, csr, dis, z2bf, N);
    spmv_final_kernel<<<spmv_blocks, 256, 0, stream>>>(z2bf, z1bf, b, startp, csr, dis, rdis,
                                                       (float*)d_out, N);
}

// Round 22
// 138.791 us; speedup vs baseline: 1.0117x; 1.0117x over previous
//
#include <hip/hip_runtime.h>
#include <math.h>
#include <string.h>

// piSGC R22: revert to R20 exactly (measured best: 139.07us).
//  R21's two trims (y-table removal + CHUNK 4096) netted -1.3us; CHUNK 4096
//  re-inflated part_scatter's scattered-write granules. This is the R20
//  config: CHUNK=8192, y table kept, g1 reconstructed from z2*rdis.
// Lineage: CSR-gather, scan-free reservation build, packed 4B csr
// (src 17b | bf16-weight 15b), bf16 z tables with diagonal push-through,
// 10-lane/node spmv (6 nodes/wave, uint2 gathers), NT output stores.

#define ALPHA  0.05f
#define SCALE  0.475f   // (1 - ALPHA) / NUM_LAYERS
#define FDIM   64
#define CDIM   40
#define NPAD   131072
#define CHUNK  8192
#define BCAP   10240
#define SRCMASK 0x1FFFFu

__device__ __forceinline__ unsigned short f2bf(float f) {
    unsigned u = __float_as_uint(f);
    unsigned r = (u + 0x7FFFu + ((u >> 16) & 1u)) >> 16;   // round-nearest-even
    return (unsigned short)r;
}
__device__ __forceinline__ float bfLo(unsigned u) { return __uint_as_float(u << 16); }
__device__ __forceinline__ float bfHi(unsigned u) { return __uint_as_float(u & 0xffff0000u); }
__device__ __forceinline__ float wUnpack(unsigned v) {
    return __uint_as_float((v >> 17) << 16);
}

// ---- zero the 256-entry alloc array ----
__global__ __launch_bounds__(256) void zero_alloc(int* __restrict__ alloc) {
    alloc[threadIdx.x] = 0;
}

// ---- part_scatter: hist chunk -> reserve ranges -> scatter packed payload ----
__global__ __launch_bounds__(1024) void part_scatter(
        const int* __restrict__ row, const int* __restrict__ col,
        const float* __restrict__ ea, int* __restrict__ alloc,
        int2* __restrict__ ppay, int E) {
    __shared__ unsigned h[256];
    __shared__ unsigned offs[256];
    int tid = threadIdx.x, blk = blockIdx.x;
    if (tid < 256) h[tid] = 0;
    __syncthreads();
    int base = blk * CHUNK;
    int end  = min(base + CHUNK, E);
    for (int e = base + tid; e < end; e += 1024)
        atomicAdd(&h[col[e] >> 9], 1u);
    __syncthreads();
    if (tid < 256) {
        unsigned hc = h[tid];
        unsigned r = hc ? (unsigned)atomicAdd(&alloc[tid], (int)hc) : 0u;
        offs[tid] = (unsigned)(tid * BCAP) + r;
    }
    __syncthreads();
    for (int e = base + tid; e < end; e += 1024) {
        int c = col[e];
        int bin = c >> 9;
        unsigned p = atomicAdd(&offs[bin], 1u);
        if (p < (unsigned)((bin + 1) * BCAP))
            ppay[p] = make_int2(row[e] | ((c & 511) << 20), __float_as_int(ea[e]));
    }
}

// ---- bucket_csr: per-bucket finalize; writes start, csr, dis AND rdis ----
__global__ __launch_bounds__(256) void bucket_csr(
        const int2* __restrict__ ppay, const int* __restrict__ alloc,
        int* __restrict__ start, unsigned* __restrict__ csr,
        float* __restrict__ dis, float* __restrict__ rdis, int N) {
    __shared__ unsigned cnt8[512][8];
    __shared__ unsigned ps[256], exc[512];
    __shared__ float sdeg[512];
    __shared__ int sAll[256];
    int tid = threadIdx.x, k = blockIdx.x;

    int myCnt = min(alloc[tid], BCAP);
    sAll[tid] = myCnt;
    __syncthreads();
    for (int off = 1; off < 256; off <<= 1) {
        int t = (tid >= off) ? sAll[tid - off] : 0;
        __syncthreads();
        sAll[tid] += t;
        __syncthreads();
    }
    int cnt = min(alloc[k], BCAP);
    int e0  = sAll[k] - cnt;
    const int2* src = ppay + (size_t)k * BCAP;

    for (int i = tid; i < 4096; i += 256) ((unsigned*)cnt8)[i] = 0;
    sdeg[tid] = 0.0f; sdeg[tid + 256] = 0.0f;
    __syncthreads();

    for (int j = tid; j < cnt; j += 256) {
        int2 pay = src[j];
        int c = (pay.x >> 20) & 511;
        atomicAdd(&cnt8[c][(pay.x & 0xFFFFF) >> 14], 1u);
        atomicAdd(&sdeg[c], __int_as_float(pay.y));
    }
    __syncthreads();

    int c0 = 2 * tid, c1 = 2 * tid + 1;
    unsigned t0 = 0, t1 = 0;
    #pragma unroll
    for (int o = 0; o < 8; ++o) { t0 += cnt8[c0][o]; t1 += cnt8[c1][o]; }
    unsigned pair = t0 + t1;
    ps[tid] = pair;
    __syncthreads();
    for (int off = 1; off < 256; off <<= 1) {
        unsigned t = (tid >= off) ? ps[tid - off] : 0;
        __syncthreads();
        ps[tid] += t;
        __syncthreads();
    }
    unsigned pexc = ps[tid] - pair;
    exc[c0] = pexc;
    exc[c1] = pexc + t0;
    unsigned b = pexc;
    #pragma unroll
    for (int o = 0; o < 8; ++o) { unsigned t = cnt8[c0][o]; cnt8[c0][o] = b; b += t; }
    b = pexc + t0;
    #pragma unroll
    for (int o = 0; o < 8; ++o) { unsigned t = cnt8[c1][o]; cnt8[c1][o] = b; b += t; }
    __syncthreads();

    #pragma unroll
    for (int i = tid; i < 512; i += 256) {
        int g = k * 512 + i;
        if (g <= N) start[g] = e0 + (int)exc[i];
        if (g < N) {
            float d = sdeg[i];
            bool pos = (d > 0.0f);
            float dc = fmaxf(d, 1e-12f);
            dis[g]  = pos ? rsqrtf(dc) : 0.0f;
            rdis[g] = pos ? sqrtf(dc)  : 0.0f;    // 1/dis
        }
    }

    for (int j = tid; j < cnt; j += 256) {
        int2 pay = src[j];
        int c    = (pay.x >> 20) & 511;
        int srcn = pay.x & 0xFFFFF;
        unsigned p = atomicAdd(&cnt8[c][srcn >> 14], 1u);
        unsigned wbf = (unsigned)f2bf(__int_as_float(pay.y));   // raw ea >= 0
        csr[e0 + p] = (unsigned)srcn | (wbf << 17);
    }
}

// ---- y = x @ W; writes y (ybf) AND z1 = dis*y. 4 threads/node x 10 outs ----
__global__ __launch_bounds__(256) void lin_kernel(
        const float* __restrict__ x, const float* __restrict__ W,
        const float* __restrict__ dis,
        unsigned* __restrict__ ybf, unsigned* __restrict__ z1, int N) {
    __shared__ float sWt[CDIM][FDIM + 4];
    for (int i = threadIdx.x; i < FDIM * CDIM; i += 256) {
        int k = i / CDIM, c = i - k * CDIM;
        sWt[c][k] = W[i];
    }
    __syncthreads();

    int t = threadIdx.x;
    int node = blockIdx.x * 64 + (t >> 2);
    if (node >= N) return;
    int cs = (t & 3) * 10;

    float acc[10];
    #pragma unroll
    for (int i = 0; i < 10; ++i) acc[i] = 0.0f;

    const float4* xr = (const float4*)(x + (size_t)node * FDIM);
    #pragma unroll
    for (int k4 = 0; k4 < FDIM / 4; ++k4) {
        float4 v = xr[k4];
        #pragma unroll
        for (int i = 0; i < 10; ++i) {
            const float4 w = *(const float4*)&sWt[cs + i][k4 * 4];
            acc[i] = fmaf(v.x, w.x, fmaf(v.y, w.y, fmaf(v.z, w.z, fmaf(v.w, w.w, acc[i]))));
        }
    }

    float dn = dis[node];
    unsigned* yr = ybf + (size_t)node * 20 + (t & 3) * 5;
    unsigned* zr = z1  + (size_t)node * 20 + (t & 3) * 5;
    #pragma unroll
    for (int k = 0; k < 5; ++k) {
        yr[k] = (unsigned)f2bf(acc[2 * k]) | ((unsigned)f2bf(acc[2 * k + 1]) << 16);
        zr[k] = (unsigned)f2bf(dn * acc[2 * k]) | ((unsigned)f2bf(dn * acc[2 * k + 1]) << 16);
    }
}

// ---- spmv1: t = A_ea^T z1; store ONLY z2 = dis^2 * t ----
__global__ __launch_bounds__(256) void spmv_kernel(
        const unsigned* __restrict__ z1, const int* __restrict__ start,
        const unsigned* __restrict__ csr, const float* __restrict__ dis,
        unsigned* __restrict__ z2, int N) {
    int lane = threadIdx.x & 63;
    int wid  = threadIdx.x >> 6;
    int grp  = lane / 10;            // 0..5 active; lanes 60-63 idle
    int grel = lane - grp * 10;
    int node = blockIdx.x * 24 + wid * 6 + grp;
    bool act = (grp < 6) && (node < N);

    int e0 = 0, e1 = 0;
    if (act) { e0 = start[node]; e1 = start[node + 1]; }
    const uint2* gin2 = (const uint2*)z1;

    float a0 = 0, a1 = 0, a2 = 0, a3 = 0;
    float b0 = 0, b1 = 0, b2 = 0, b3 = 0;
    int j = e0;
    for (; j + 7 < e1; j += 8) {
        unsigned v0 = csr[j],     v1 = csr[j + 1], v2 = csr[j + 2], v3 = csr[j + 3];
        unsigned v4 = csr[j + 4], v5 = csr[j + 5], v6 = csr[j + 6], v7 = csr[j + 7];
        uint2 u0 = gin2[(size_t)(v0 & SRCMASK) * 10 + grel];
        uint2 u1 = gin2[(size_t)(v1 & SRCMASK) * 10 + grel];
        uint2 u2 = gin2[(size_t)(v2 & SRCMASK) * 10 + grel];
        uint2 u3 = gin2[(size_t)(v3 & SRCMASK) * 10 + grel];
        uint2 u4 = gin2[(size_t)(v4 & SRCMASK) * 10 + grel];
        uint2 u5 = gin2[(size_t)(v5 & SRCMASK) * 10 + grel];
        uint2 u6 = gin2[(size_t)(v6 & SRCMASK) * 10 + grel];
        uint2 u7 = gin2[(size_t)(v7 & SRCMASK) * 10 + grel];
        float w0 = wUnpack(v0), w1 = wUnpack(v1), w2 = wUnpack(v2), w3 = wUnpack(v3);
        float w4 = wUnpack(v4), w5 = wUnpack(v5), w6 = wUnpack(v6), w7 = wUnpack(v7);
        a0 = fmaf(w0, bfLo(u0.x), a0); a1 = fmaf(w0, bfHi(u0.x), a1);
        a2 = fmaf(w0, bfLo(u0.y), a2); a3 = fmaf(w0, bfHi(u0.y), a3);
        b0 = fmaf(w1, bfLo(u1.x), b0); b1 = fmaf(w1, bfHi(u1.x), b1);
        b2 = fmaf(w1, bfLo(u1.y), b2); b3 = fmaf(w1, bfHi(u1.y), b3);
        a0 = fmaf(w2, bfLo(u2.x), a0); a1 = fmaf(w2, bfHi(u2.x), a1);
        a2 = fmaf(w2, bfLo(u2.y), a2); a3 = fmaf(w2, bfHi(u2.y), a3);
        b0 = fmaf(w3, bfLo(u3.x), b0); b1 = fmaf(w3, bfHi(u3.x), b1);
        b2 = fmaf(w3, bfLo(u3.y), b2); b3 = fmaf(w3, bfHi(u3.y), b3);
        a0 = fmaf(w4, bfLo(u4.x), a0); a1 = fmaf(w4, bfHi(u4.x), a1);
        a2 = fmaf(w4, bfLo(u4.y), a2); a3 = fmaf(w4, bfHi(u4.y), a3);
        b0 = fmaf(w5, bfLo(u5.x), b0); b1 = fmaf(w5, bfHi(u5.x), b1);
        b2 = fmaf(w5, bfLo(u5.y), b2); b3 = fmaf(w5, bfHi(u5.y), b3);
        a0 = fmaf(w6, bfLo(u6.x), a0); a1 = fmaf(w6, bfHi(u6.x), a1);
        a2 = fmaf(w6, bfLo(u6.y), a2); a3 = fmaf(w6, bfHi(u6.y), a3);
        b0 = fmaf(w7, bfLo(u7.x), b0); b1 = fmaf(w7, bfHi(u7.x), b1);
        b2 = fmaf(w7, bfLo(u7.y), b2); b3 = fmaf(w7, bfHi(u7.y), b3);
    }
    for (; j < e1; ++j) {
        unsigned v = csr[j];
        uint2 u = gin2[(size_t)(v & SRCMASK) * 10 + grel];
        float w = wUnpack(v);
        a0 = fmaf(w, bfLo(u.x), a0); a1 = fmaf(w, bfHi(u.x), a1);
        a2 = fmaf(w, bfLo(u.y), a2); a3 = fmaf(w, bfHi(u.y), a3);
    }
    if (act) {
        float dn = dis[node];
        float d2 = dn * dn;
        float z0 = d2 * (a0 + b0), zz1 = d2 * (a1 + b1);
        float z2v = d2 * (a2 + b2), z3 = d2 * (a3 + b3);
        uint2 oz;
        oz.x = (unsigned)f2bf(z0)  | ((unsigned)f2bf(zz1) << 16);
        oz.y = (unsigned)f2bf(z2v) | ((unsigned)f2bf(z3) << 16);
        ((uint2*)z2)[(size_t)node * 10 + grel] = oz;
    }
}

// ---- conv2 + log_softmax; g1 reconstructed as z2[node]*rdis[node] ----
__global__ __launch_bounds__(256) void spmv_final_kernel(
        const unsigned* __restrict__ z2, const unsigned* __restrict__ y,
        const float* __restrict__ bias, const int* __restrict__ start,
        const unsigned* __restrict__ csr, const float* __restrict__ dis,
        const float* __restrict__ rdis, float* __restrict__ out, int N) {
    int lane = threadIdx.x & 63;
    int wid  = threadIdx.x >> 6;
    int grp  = lane / 10;
    int grel = lane - grp * 10;
    int node = blockIdx.x * 24 + wid * 6 + grp;
    bool act = (grp < 6) && (node < N);

    int e0 = 0, e1 = 0;
    if (act) { e0 = start[node]; e1 = start[node + 1]; }
    const uint2* g22 = (const uint2*)z2;

    float a0 = 0, a1 = 0, a2 = 0, a3 = 0;
    float b0 = 0, b1 = 0, b2 = 0, b3 = 0;
    int j = e0;
    for (; j + 7 < e1; j += 8) {
        unsigned v0 = csr[j],     v1 = csr[j + 1], v2 = csr[j + 2], v3 = csr[j + 3];
        unsigned v4 = csr[j + 4], v5 = csr[j + 5], v6 = csr[j + 6], v7 = csr[j + 7];
        uint2 u0 = g22[(size_t)(v0 & SRCMASK) * 10 + grel];
        uint2 u1 = g22[(size_t)(v1 & SRCMASK) * 10 + grel];
        uint2 u2 = g22[(size_t)(v2 & SRCMASK) * 10 + grel];
        uint2 u3 = g22[(size_t)(v3 & SRCMASK) * 10 + grel];
        uint2 u4 = g22[(size_t)(v4 & SRCMASK) * 10 + grel];
        uint2 u5 = g22[(size_t)(v5 & SRCMASK) * 10 + grel];
        uint2 u6 = g22[(size_t)(v6 & SRCMASK) * 10 + grel];
        uint2 u7 = g22[(size_t)(v7 & SRCMASK) * 10 + grel];
        float w0 = wUnpack(v0), w1 = wUnpack(v1), w2 = wUnpack(v2), w3 = wUnpack(v3);
        float w4 = wUnpack(v4), w5 = wUnpack(v5), w6 = wUnpack(v6), w7 = wUnpack(v7);
        a0 = fmaf(w0, bfLo(u0.x), a0); a1 = fmaf(w0, bfHi(u0.x), a1);
        a2 = fmaf(w0, bfLo(u0.y), a2); a3 = fmaf(w0, bfHi(u0.y), a3);
        b0 = fmaf(w1, bfLo(u1.x), b0); b1 = fmaf(w1, bfHi(u1.x), b1);
        b2 = fmaf(w1, bfLo(u1.y), b2); b3 = fmaf(w1, bfHi(u1.y), b3);
        a0 = fmaf(w2, bfLo(u2.x), a0); a1 = fmaf(w2, bfHi(u2.x), a1);
        a2 = fmaf(w2, bfLo(u2.y), a2); a3 = fmaf(w2, bfHi(u2.y), a3);
        b0 = fmaf(w3, bfLo(u3.x), b0); b1 = fmaf(w3, bfHi(u3.x), b1);
        b2 = fmaf(w3, bfLo(u3.y), b2); b3 = fmaf(w3, bfHi(u3.y), b3);
        a0 = fmaf(w4, bfLo(u4.x), a0); a1 = fmaf(w4, bfHi(u4.x), a1);
        a2 = fmaf(w4, bfLo(u4.y), a2); a3 = fmaf(w4, bfHi(u4.y), a3);
        b0 = fmaf(w5, bfLo(u5.x), b0); b1 = fmaf(w5, bfHi(u5.x), b1);
        b2 = fmaf(w5, bfLo(u5.y), b2); b3 = fmaf(w5, bfHi(u5.y), b3);
        a0 = fmaf(w6, bfLo(u6.x), a0); a1 = fmaf(w6, bfHi(u6.x), a1);
        a2 = fmaf(w6, bfLo(u6.y), a2); a3 = fmaf(w6, bfHi(u6.y), a3);
        b0 = fmaf(w7, bfLo(u7.x), b0); b1 = fmaf(w7, bfHi(u7.x), b1);
        b2 = fmaf(w7, bfLo(u7.y), b2); b3 = fmaf(w7, bfHi(u7.y), b3);
    }
    for (; j < e1; ++j) {
        unsigned v = csr[j];
        uint2 u = g22[(size_t)(v & SRCMASK) * 10 + grel];
        float w = wUnpack(v);
        a0 = fmaf(w, bfLo(u.x), a0); a1 = fmaf(w, bfHi(u.x), a1);
        a2 = fmaf(w, bfLo(u.y), a2); a3 = fmaf(w, bfHi(u.y), a3);
    }

    float l0 = 0, l1 = 0, l2 = 0, l3 = 0;
    if (act) {
        float dn = dis[node];
        float rd = rdis[node];
        float g20 = dn * (a0 + b0), g21 = dn * (a1 + b1);
        float g22v = dn * (a2 + b2), g23 = dn * (a3 + b3);
        uint2 yu = ((const uint2*)y)[(size_t)node * 10 + grel];
        uint2 zu = g22[(size_t)node * 10 + grel];
        float g10 = bfLo(zu.x) * rd, g11 = bfHi(zu.x) * rd;
        float g12 = bfLo(zu.y) * rd, g13 = bfHi(zu.y) * rd;
        float4 bv = *(const float4*)&bias[4 * grel];
        l0 = fmaf(ALPHA, bfLo(yu.x), fmaf(SCALE, g10 + g20, bv.x));
        l1 = fmaf(ALPHA, bfHi(yu.x), fmaf(SCALE, g11 + g21, bv.y));
        l2 = fmaf(ALPHA, bfLo(yu.y), fmaf(SCALE, g12 + g22v, bv.z));
        l3 = fmaf(ALPHA, bfHi(yu.y), fmaf(SCALE, g13 + g23, bv.w));
    }

    float m = act ? fmaxf(fmaxf(l0, l1), fmaxf(l2, l3)) : -INFINITY;
    #pragma unroll
    for (int off = 8; off; off >>= 1) {
        float o = __shfl(m, lane + off);
        if (grel + off < 10) m = fmaxf(m, o);
    }
    m = __shfl(m, grp * 10);

    float ex = act ? (expf(l0 - m) + expf(l1 - m) + expf(l2 - m) + expf(l3 - m)) : 0.0f;
    #pragma unroll
    for (int off = 8; off; off >>= 1) {
        float o = __shfl(ex, lane + off);
        if (grel + off < 10) ex += o;
    }
    ex = __shfl(ex, grp * 10);

    if (act) {
        float lse = m + logf(ex);
        float2 oA, oB;
        oA.x = l0 - lse; oA.y = l1 - lse;
        oB.x = l2 - lse; oB.y = l3 - lse;
        double dA, dB;
        memcpy(&dA, &oA, 8);
        memcpy(&dB, &oB, 8);
        double* p = (double*)&out[(size_t)node * CDIM + 4 * grel];
        __builtin_nontemporal_store(dA, p);
        __builtin_nontemporal_store(dB, p + 1);
    }
}

extern "C" void kernel_launch(void* const* d_in, const int* in_sizes, int n_in,
                              void* d_out, int out_size, void* d_ws, size_t ws_size,
                              hipStream_t stream) {
    const float* x  = (const float*)d_in[0];   // [N,64]
    const float* ea = (const float*)d_in[1];   // [E]
    const float* W  = (const float*)d_in[2];   // [64,40]
    const float* b  = (const float*)d_in[3];   // [40]
    const int*   ei = (const int*)d_in[4];     // [2,E]: row then col

    const int N = in_sizes[0] / FDIM;
    const int E = in_sizes[1];
    const int* row = ei;
    const int* col = ei + E;

    const int NBLK = (E + CHUNK - 1) / CHUNK;

    // workspace layout (4-byte words; every used region fully written each call)
    int*   startp = (int*)d_ws;                    // NPAD
    float* dis    = (float*)(startp + NPAD);       // NPAD
    float* rdis   = dis + NPAD;                    // NPAD
    int*   alloc  = (int*)(rdis + NPAD);           // 1024 (256 used)
    int2*  ppay   = (int2*)(alloc + 1024);         // 256*BCAP int2 (~21 MB)
    unsigned* csr = (unsigned*)(ppay + 256 * BCAP); // E packed dwords
    unsigned* z2bf = csr + E;                      // N*20 dwords
    unsigned* ybf  = (unsigned*)ppay;              // aliases ppay (dead after bucket_csr)
    unsigned* z1bf = ybf + (size_t)N * 20;         // still inside ppay region (16MB < 21MB)

    zero_alloc  <<<1, 256, 0, stream>>>(alloc);
    part_scatter<<<NBLK, 1024, 0, stream>>>(row, col, ea, alloc, ppay, E);
    bucket_csr  <<<256, 256, 0, stream>>>(ppay, alloc, startp, csr, dis, rdis, N);
    lin_kernel  <<<(N + 63) / 64, 256, 0, stream>>>(x, W, dis, ybf, z1bf, N);

    int spmv_blocks = (N + 23) / 24;
    spmv_kernel      <<<spmv_blocks, 256, 0, stream>>>(z1bf, startp, csr, dis, z2bf, N);
    spmv_final_kernel<<<spmv_blocks, 256, 0, stream>>>(z2bf, ybf, b, startp, csr, dis, rdis,
                                                       (float*)d_out, N);
}